// Round 1
// baseline (235.281 us; speedup 1.0000x reference)
//
#include <hip/hip_runtime.h>

// ---------------------------------------------------------------------------
// ActorCritic fused loss, MI355X.
//   T=8192, B=4096 (hardcoded from reference shapes).
//   Pipeline: k_detect (mask dtype probe) -> k_scan (chunk-local discounted
//   sums) -> k_carry (cross-chunk carries) -> k_main (fused re-scan + 10
//   masked sums) -> k_final (closed-form losses).
// ---------------------------------------------------------------------------

constexpr int T  = 8192;
constexpr int B  = 4096;
constexpr int L  = 32;           // chunk length along T
constexpr int NC = T / L;        // 256 chunks
constexpr int B4 = B / 4;        // 1024 float4 columns
constexpr int BLK = 256;
constexpr int WAVES = BLK / 64;
constexpr int MAIN_BLOCKS = (NC * B4) / BLK;   // 1024

constexpr float GAMMA_F = 0.99f;

constexpr double cpow(double g, int n) { double r = 1.0; for (int i = 0; i < n; ++i) r *= g; return r; }
constexpr float GL = (float)cpow(0.99, L);     // gamma^L

// workspace layout (bytes)
constexpr size_t S_OFF = 0;                                     // NC*B4 float4  (4 MiB)
constexpr size_t H_OFF = (size_t)NC * B4 * 16;                  // 4 MiB
constexpr size_t P_OFF = 2 * H_OFF;                             // 8 MiB: MAIN_BLOCKS*10 doubles
constexpr size_t F_OFF = P_OFF + (size_t)MAIN_BLOCKS * 10 * 8;  // +80 KiB: flag int

// --------------------------------------------------------------------------
// Probe mask layout: int32 {0,1} little-endian has bytes 1..3 of every
// element == 0. Random 0/1 bytes (bool layout) cannot. Reads 64 KiB, which is
// within the buffer in either layout.
__global__ void __launch_bounds__(BLK) k_detect(const unsigned char* __restrict__ m,
                                                int* __restrict__ flag) {
    __shared__ unsigned sh[WAVES];
    unsigned v = 0;
    for (int i = threadIdx.x; i < 65536; i += BLK)
        if (i & 3) v |= m[i];
    #pragma unroll
    for (int off = 32; off; off >>= 1) v |= __shfl_down(v, off);
    if ((threadIdx.x & 63) == 0) sh[threadIdx.x >> 6] = v;
    __syncthreads();
    if (threadIdx.x == 0) {
        unsigned r = 0;
        #pragma unroll
        for (int w = 0; w < WAVES; ++w) r |= sh[w];
        *flag = (r == 0) ? 1 : 0;   // 1 => int32 layout
    }
}

// --------------------------------------------------------------------------
// Per-chunk local discounted suffix sum (zero init): S_c = sum_i gamma^i r[cL+i].
__global__ void __launch_bounds__(BLK) k_scan(const float4* __restrict__ rw,
                                              float4* __restrict__ S) {
    int idx = blockIdx.x * BLK + threadIdx.x;
    int c = idx / B4;
    int b = idx - c * B4;
    const float4* p = rw + (size_t)c * L * B4 + b;
    float4 a = make_float4(0.f, 0.f, 0.f, 0.f);
    #pragma unroll 8
    for (int i = L - 1; i >= 0; --i) {
        float4 r = p[i * B4];
        a.x = fmaf(GAMMA_F, a.x, r.x);
        a.y = fmaf(GAMMA_F, a.y, r.y);
        a.z = fmaf(GAMMA_F, a.z, r.z);
        a.w = fmaf(GAMMA_F, a.w, r.w);
    }
    S[(size_t)c * B4 + b] = a;
}

// --------------------------------------------------------------------------
// Cross-chunk carries: H_c = G at index (c+1)*L.  H_{NC-1}=0; H_{c-1}=S_c+GL*H_c.
__global__ void __launch_bounds__(BLK) k_carry(const float4* __restrict__ S,
                                               float4* __restrict__ H) {
    int b = blockIdx.x * BLK + threadIdx.x;   // 0..B4-1
    float4 h = make_float4(0.f, 0.f, 0.f, 0.f);
    #pragma unroll 8
    for (int c = NC - 1; c >= 0; --c) {
        float4 s = S[(size_t)c * B4 + b];
        H[(size_t)c * B4 + b] = h;
        h.x = fmaf(GL, h.x, s.x);
        h.y = fmaf(GL, h.y, s.y);
        h.z = fmaf(GL, h.z, s.z);
        h.w = fmaf(GL, h.w, s.w);
    }
}

// --------------------------------------------------------------------------
// Fused pass: recompute G per element (chunk Horner seeded with carry) and
// accumulate the 10 masked sums.
#define COMP(MJ, GX, RX, VX, LX, ZX)                 \
    do {                                             \
        GX = fmaf(GAMMA_F, GX, RX);                  \
        float mm = (MJ);                             \
        float Gm = mm * GX;                          \
        float vm = mm * VX;                          \
        float lm = mm * LX;                          \
        a0 += mm;                                    \
        a1 += Gm;                                    \
        a2 = fmaf(Gm, GX, a2);                       \
        a3 = fmaf(Gm, VX, a3);                       \
        a4 += vm;                                    \
        a5 = fmaf(vm, VX, a5);                       \
        a6 = fmaf(lm, GX, a6);                       \
        a7 += lm;                                    \
        a8 = fmaf(mm, ZX, a8);                       \
        a9 = fmaf(lm, VX, a9);                       \
    } while (0)

#define ITER_BODY(MASKLOAD)                          \
    _Pragma("unroll 4")                              \
    for (int i = L - 1; i >= 0; --i) {               \
        int e = base + i * B4;                       \
        float4 r = rw[e];                            \
        float4 v = vv[e];                            \
        float4 l = lq[e];                            \
        float4 z = en[e];                            \
        float m0, m1, m2, m3;                        \
        MASKLOAD;                                    \
        COMP(m0, G.x, r.x, v.x, l.x, z.x);           \
        COMP(m1, G.y, r.y, v.y, l.y, z.y);           \
        COMP(m2, G.z, r.z, v.z, l.z, z.z);           \
        COMP(m3, G.w, r.w, v.w, l.w, z.w);           \
    }

__global__ void __launch_bounds__(BLK) k_main(const float4* __restrict__ rw,
                                              const float4* __restrict__ vv,
                                              const float4* __restrict__ lq,
                                              const float4* __restrict__ en,
                                              const void* __restrict__ mp,
                                              const int* __restrict__ flag,
                                              const float4* __restrict__ H,
                                              double* __restrict__ partials) {
    int idx = blockIdx.x * BLK + threadIdx.x;
    int c = idx / B4;
    int b = idx - c * B4;
    float4 G = H[(size_t)c * B4 + b];
    int base = c * L * B4 + b;
    float a0 = 0.f, a1 = 0.f, a2 = 0.f, a3 = 0.f, a4 = 0.f;
    float a5 = 0.f, a6 = 0.f, a7 = 0.f, a8 = 0.f, a9 = 0.f;

    const bool i32 = (*flag != 0);
    if (i32) {
        ITER_BODY({
            int4 q = ((const int4*)mp)[e];
            m0 = q.x ? 1.f : 0.f; m1 = q.y ? 1.f : 0.f;
            m2 = q.z ? 1.f : 0.f; m3 = q.w ? 1.f : 0.f;
        });
    } else {
        ITER_BODY({
            uchar4 q = ((const uchar4*)mp)[e];
            m0 = q.x ? 1.f : 0.f; m1 = q.y ? 1.f : 0.f;
            m2 = q.z ? 1.f : 0.f; m3 = q.w ? 1.f : 0.f;
        });
    }

    // deterministic block reduction in f64
    double d[10] = {a0, a1, a2, a3, a4, a5, a6, a7, a8, a9};
    #pragma unroll
    for (int k = 0; k < 10; ++k)
        #pragma unroll
        for (int off = 32; off; off >>= 1)
            d[k] += __shfl_down(d[k], off);

    __shared__ double sh[WAVES][10];
    int lane = threadIdx.x & 63, w = threadIdx.x >> 6;
    if (lane == 0) {
        #pragma unroll
        for (int k = 0; k < 10; ++k) sh[w][k] = d[k];
    }
    __syncthreads();
    if (threadIdx.x == 0) {
        #pragma unroll
        for (int k = 0; k < 10; ++k) {
            double s = sh[0][k];
            #pragma unroll
            for (int ww = 1; ww < WAVES; ++ww) s += sh[ww][k];
            partials[(size_t)blockIdx.x * 10 + k] = s;
        }
    }
}

// --------------------------------------------------------------------------
__global__ void __launch_bounds__(BLK) k_final(const double* __restrict__ partials,
                                               float* __restrict__ out) {
    double d[10];
    #pragma unroll
    for (int k = 0; k < 10; ++k) d[k] = 0.0;
    for (int i = threadIdx.x; i < MAIN_BLOCKS; i += BLK) {
        #pragma unroll
        for (int k = 0; k < 10; ++k) d[k] += partials[(size_t)i * 10 + k];
    }
    #pragma unroll
    for (int k = 0; k < 10; ++k)
        #pragma unroll
        for (int off = 32; off; off >>= 1)
            d[k] += __shfl_down(d[k], off);

    __shared__ double sh[WAVES][10];
    int lane = threadIdx.x & 63, w = threadIdx.x >> 6;
    if (lane == 0) {
        #pragma unroll
        for (int k = 0; k < 10; ++k) sh[w][k] = d[k];
    }
    __syncthreads();
    if (threadIdx.x == 0) {
        double s[10];
        #pragma unroll
        for (int k = 0; k < 10; ++k) {
            double t = sh[0][k];
            #pragma unroll
            for (int ww = 1; ww < WAVES; ++ww) t += sh[ww][k];
            s[k] = t;
        }
        double n = s[0], SG = s[1], SG2 = s[2], SGv = s[3], Sv = s[4];
        double Sv2 = s[5], SlpG = s[6], Slp = s[7], Sent = s[8], Slpv = s[9];

        double mean = SG / n;
        double css  = SG2 - 2.0 * mean * SG + mean * mean * n;  // sum m*(G-mean)^2
        double var  = css / (n - 1.0);
        double sd   = sqrt(var);
        double sc   = 1.0 / (sd + 1e-8);

        double critic = sc * sc * css - 2.0 * sc * (SGv - mean * Sv) + Sv2;
        double actor  = -sc * (SlpG - mean * Slp) + Slpv - 0.01 * Sent;

        out[0] = (float)critic;
        out[1] = (float)actor;
    }
}

// --------------------------------------------------------------------------
extern "C" void kernel_launch(void* const* d_in, const int* in_sizes, int n_in,
                              void* d_out, int out_size, void* d_ws, size_t ws_size,
                              hipStream_t stream) {
    const float4* rw = (const float4*)d_in[0];
    const float4* vv = (const float4*)d_in[1];
    const float4* lq = (const float4*)d_in[2];
    const float4* en = (const float4*)d_in[3];
    const void*   mp = d_in[4];

    char* ws = (char*)d_ws;
    float4* S        = (float4*)(ws + S_OFF);
    float4* H        = (float4*)(ws + H_OFF);
    double* partials = (double*)(ws + P_OFF);
    int*    flag     = (int*)(ws + F_OFF);

    k_detect<<<1, BLK, 0, stream>>>((const unsigned char*)mp, flag);
    k_scan  <<<MAIN_BLOCKS, BLK, 0, stream>>>(rw, S);
    k_carry <<<B4 / BLK, BLK, 0, stream>>>(S, H);
    k_main  <<<MAIN_BLOCKS, BLK, 0, stream>>>(rw, vv, lq, en, mp, flag, H, partials);
    k_final <<<1, BLK, 0, stream>>>(partials, (float*)d_out);
}